// Round 5
// baseline (729.025 us; speedup 1.0000x reference)
//
#include <hip/hip_runtime.h>

// CRF log-partition forward, MI355X. 64 blocks (1 per sequence) x 64 threads
// (ONE wave -> no __syncthreads, no vmcnt(0) barrier drains).
// Lane l owns tag pair {2l, 2l+1}; E column-pair lives in registers
// (f2 E[128], 256 VGPRs; 1 wave/SIMD so no occupancy cost, spill at ~512).
// Per step: ds_write_b64 own p pair -> 8x ds_read_b128 broadcast of all 128
// p's -> 128 v_pk_fma_f32 (4 chains) -> scale+exp tail -> next step.
// In-wave DS ordering makes the single LDS buffer safe (reads of step t+1
// are issued after the write of step t in program order).
//
// Normalizer is all-scalar: readfirstlane(q_0) -> exponent -> SGPR o/scale.
//   q'_j = exp2(e_j*log2e) * (sum_i q_i E_ij) * 2^(-eS),  eS = exponent(q_0)
//   o    += eS (integer, exact);  alpha_j = ln2 * (o + log2 q_j)
//
// Emissions prefetched DISTANCE-3 through a manually unrolled 3-slot register
// ring (no rotate movs -> loads stay in flight across ~3 steps ~ HBM latency).

#define LOG2E 1.4426950408889634f
#define LN2   0.6931471805599453f

typedef float f2 __attribute__((ext_vector_type(2)));

__global__ __launch_bounds__(64, 1) void crf_forward(
    const float* __restrict__ emissions,   // [64, 512, 128]
    const float* __restrict__ transitions, // [128, 128]
    const float* __restrict__ start_t,     // [128]
    const float* __restrict__ end_t,       // [128]
    const int*   __restrict__ lengths,     // [64]
    float* __restrict__ out)               // [64]
{
    constexpr int N = 128;
    constexpr int L = 512;
    const int b = blockIdx.x;
    const int l = threadIdx.x;       // lane 0..63, owns tags 2l and 2l+1

    __shared__ alignas(16) float pbuf[N];

    // ---- one-time: E column pair in registers.
    // E[i] = exp2(T[i][2l + {0,1}] * log2e), i = 0..127  (256 VGPRs)
    f2 E[N];
    {
        const float* tb = transitions + 2 * l;
        #pragma unroll
        for (int i = 0; i < N; ++i) {
            f2 tv = *reinterpret_cast<const f2*>(tb + (size_t)i * N);
            E[i].x = __builtin_amdgcn_exp2f(tv.x * LOG2E);
            E[i].y = __builtin_amdgcn_exp2f(tv.y * LOG2E);
        }
    }

    const int len = lengths[b];
    const float* embase = emissions + (size_t)b * L * N + 2 * l;

    // ---- init: p = exp2((start + e0) * log2e) for tags {2l, 2l+1}
    f2 st = *reinterpret_cast<const f2*>(start_t + 2 * l);
    f2 e0 = *reinterpret_cast<const f2*>(embase);
    f2 p;
    p.x = __builtin_amdgcn_exp2f((st.x + e0.x) * LOG2E);
    p.y = __builtin_amdgcn_exp2f((st.y + e0.y) * LOG2E);
    int o = 0;
    *reinterpret_cast<f2*>(&pbuf[2 * l]) = p;

    // one step of the recurrence; ecur = emissions for this t
    auto STEP = [&](f2 ecur) {
        // broadcast-read all 128 p's (8x ds_read_b128, same addr across lanes)
        const float4* pv = reinterpret_cast<const float4*>(pbuf);
        float4 v[8];
        #pragma unroll
        for (int w = 0; w < 8; ++w) v[w] = pv[w];

        // scalar normalizer from previous q_0 (lane 0 owns tag 0)
        unsigned pu = (unsigned)__builtin_amdgcn_readfirstlane(
            (int)__float_as_uint(p.x));
        int eS = (int)((pu >> 23) & 0xFFu) - 127;
        o += eS;
        float scale = __uint_as_float((unsigned)(127 - eS) << 23);

        // 128 pk-FMAs, 4 independent chains
        f2 a0 = {0.f, 0.f}, a1 = {0.f, 0.f}, a2 = {0.f, 0.f}, a3 = {0.f, 0.f};
        #pragma unroll
        for (int w = 0; w < 8; ++w) {
            float pe0 = v[w].x, pe1 = v[w].y, pe2 = v[w].z, pe3 = v[w].w;
            f2 q0 = {pe0, pe0}, q1 = {pe1, pe1}, q2 = {pe2, pe2}, q3 = {pe3, pe3};
            a0 = __builtin_elementwise_fma(q0, E[w * 4 + 0], a0);
            a1 = __builtin_elementwise_fma(q1, E[w * 4 + 1], a1);
            a2 = __builtin_elementwise_fma(q2, E[w * 4 + 2], a2);
            a3 = __builtin_elementwise_fma(q3, E[w * 4 + 3], a3);
        }
        #pragma unroll
        for (int w = 0; w < 8; ++w) {
            float pe0 = v[w].x, pe1 = v[w].y, pe2 = v[w].z, pe3 = v[w].w;
            f2 q0 = {pe0, pe0}, q1 = {pe1, pe1}, q2 = {pe2, pe2}, q3 = {pe3, pe3};
            a0 = __builtin_elementwise_fma(q0, E[32 + w * 4 + 0], a0);
            a1 = __builtin_elementwise_fma(q1, E[32 + w * 4 + 1], a1);
            a2 = __builtin_elementwise_fma(q2, E[32 + w * 4 + 2], a2);
            a3 = __builtin_elementwise_fma(q3, E[32 + w * 4 + 3], a3);
        }
        f2 d = (a0 + a1) + (a2 + a3);

        f2 ex;
        ex.x = __builtin_amdgcn_exp2f(ecur.x * LOG2E);
        ex.y = __builtin_amdgcn_exp2f(ecur.y * LOG2E);
        p.x = ex.x * d.x * scale;
        p.y = ex.y * d.y * scale;

        // publish for next step (in-wave DS ordering: next step's reads,
        // issued later in program order, will see this write)
        *reinterpret_cast<f2*>(&pbuf[2 * l]) = p;
    };
    // NOTE: E is read as E[w*4+e] with i = w*4+e over 0..31 then 32..63 —
    // that covers i=0..63; second half handled below via the same lambda
    // pattern applied to chunks 2,3. To keep i-coverage complete we fold the
    // remaining chunks into the loops above: v[w] holds p[4w..4w+3] for
    // w=0..7, i.e. ALL 32 float4 of the 128 p's are in v[0..7]? No — 8
    // float4 = 32 floats. See corrected indexing below.

    // ---- corrected STEP (full 128-i coverage): read 32 float4, FMA over all
    auto STEP_FULL = [&](f2 ecur) {
        const float4* pv = reinterpret_cast<const float4*>(pbuf);
        unsigned pu = (unsigned)__builtin_amdgcn_readfirstlane(
            (int)__float_as_uint(p.x));
        int eS = (int)((pu >> 23) & 0xFFu) - 127;
        o += eS;
        float scale = __uint_as_float((unsigned)(127 - eS) << 23);

        f2 a0 = {0.f, 0.f}, a1 = {0.f, 0.f}, a2 = {0.f, 0.f}, a3 = {0.f, 0.f};
        #pragma unroll
        for (int c = 0; c < 4; ++c) {           // 4 chunks of 32 i's
            float4 v[8];
            #pragma unroll
            for (int w = 0; w < 8; ++w) v[w] = pv[c * 8 + w];
            #pragma unroll
            for (int w = 0; w < 8; ++w) {
                const int base = c * 32 + w * 4;
                f2 q0 = {v[w].x, v[w].x}, q1 = {v[w].y, v[w].y};
                f2 q2 = {v[w].z, v[w].z}, q3 = {v[w].w, v[w].w};
                a0 = __builtin_elementwise_fma(q0, E[base + 0], a0);
                a1 = __builtin_elementwise_fma(q1, E[base + 1], a1);
                a2 = __builtin_elementwise_fma(q2, E[base + 2], a2);
                a3 = __builtin_elementwise_fma(q3, E[base + 3], a3);
            }
        }
        f2 d = (a0 + a1) + (a2 + a3);

        f2 ex;
        ex.x = __builtin_amdgcn_exp2f(ecur.x * LOG2E);
        ex.y = __builtin_amdgcn_exp2f(ecur.y * LOG2E);
        p.x = ex.x * d.x * scale;
        p.y = ex.y * d.y * scale;
        *reinterpret_cast<f2*>(&pbuf[2 * l]) = p;
    };
    (void)STEP;   // superseded by STEP_FULL

    // ---- main loop: distance-3 emission prefetch, manual 3-way unroll
    auto ldE = [&](int tt) {
        return *reinterpret_cast<const f2*>(embase + (size_t)tt * N);
    };
    auto clampt = [&](int tt) { return tt < len ? tt : len - 1; };

    f2 ra = ldE(clampt(1));
    f2 rb = ldE(clampt(2));
    f2 rc = ldE(clampt(3));

    int t = 1;
    for (;;) {
        if (t >= len) break;
        STEP_FULL(ra); ra = ldE(clampt(t + 3)); ++t;
        if (t >= len) break;
        STEP_FULL(rb); rb = ldE(clampt(t + 3)); ++t;
        if (t >= len) break;
        STEP_FULL(rc); rc = ldE(clampt(t + 3)); ++t;
    }

    // ---- finalize: out[b] = ln2 * (o + log2(sum_j q_j * exp2(end_j*log2e)))
    f2 ef = *reinterpret_cast<const f2*>(end_t + 2 * l);
    float vend = p.x * __builtin_amdgcn_exp2f(ef.x * LOG2E)
               + p.y * __builtin_amdgcn_exp2f(ef.y * LOG2E);
    #pragma unroll
    for (int m = 1; m < 64; m <<= 1) vend += __shfl_xor(vend, m);
    if (l == 0)
        out[b] = LN2 * ((float)o + __builtin_amdgcn_logf(vend));
}

extern "C" void kernel_launch(void* const* d_in, const int* in_sizes, int n_in,
                              void* d_out, int out_size, void* d_ws, size_t ws_size,
                              hipStream_t stream) {
    const float* emissions   = (const float*)d_in[0];
    const float* transitions = (const float*)d_in[1];
    const float* start_t     = (const float*)d_in[2];
    const float* end_t       = (const float*)d_in[3];
    const int*   lengths     = (const int*)d_in[4];
    float* out = (float*)d_out;

    crf_forward<<<dim3(64), dim3(64), 0, stream>>>(
        emissions, transitions, start_t, end_t, lengths, out);
}

// Round 6
// 207.600 us; speedup vs baseline: 3.5117x; 3.5117x over previous
//
#include <hip/hip_runtime.h>

// CRF log-partition forward, MI355X. 64 blocks (1 per sequence) x 256 threads
// (4 waves, 1/SIMD). Lane tile: k = tid&7 -> i-chunk [16k,16k+16),
// g = tid>>3 -> j in [4g,4g+4). Two float2 accumulators (v_pk_fma_f32).
// Combine: DPP quad butterfly (xor1,xor2), select target column, single
// ds_swizzle xor4. Writers k<4 store tag j = 4g+k.
//
// KEY change vs round 4: __syncthreads() emitted s_waitcnt vmcnt(0) before
// every s_barrier, draining the emission prefetch (HBM latency ~900 cyc) into
// every step. Cross-wave communication here is LDS-only, so an inline-asm
// barrier with ONLY lgkmcnt(0) is sufficient -> global loads stay in flight.
// Emission prefetch deepened to distance 4 (4-slot unrolled register ring).
//
// Linear-domain recurrence with exact power-of-2 renormalization:
//   q'_j = exp2(e_j*log2e) * (sum_i q_i E_ij) * 2^(-eS),  eS = exponent(q_0)
//   o    += eS   (integer, exact)
// alpha_j = ln2 * (o + log2 q_j). Final: ln2*(o + log2 sum_j q_j*exp(end_j)).

#define LOG2E 1.4426950408889634f
#define LN2   0.6931471805599453f

// LDS-only workgroup barrier: no vmcnt drain (cross-wave data is LDS only).
#define LDS_BARRIER() asm volatile("s_waitcnt lgkmcnt(0)\n\ts_barrier" ::: "memory")

typedef float f2 __attribute__((ext_vector_type(2)));

template <int CTRL>
__device__ __forceinline__ float dpp_f(float x) {
    return __int_as_float(
        __builtin_amdgcn_mov_dpp(__float_as_int(x), CTRL, 0xF, 0xF, false));
}
template <int CTRL>
__device__ __forceinline__ f2 dpp_f2(f2 x) {
    f2 r;
    r.x = dpp_f<CTRL>(x.x);
    r.y = dpp_f<CTRL>(x.y);
    return r;
}
// quad_perm codes: xor1 = 0xB1, xor2 = 0x4E
__device__ __forceinline__ float swz_xor4(float x) {
    // BitMode: offset = (xor<<10)|(or<<5)|and ; xor=4, and=0x1F
    return __int_as_float(
        __builtin_amdgcn_ds_swizzle(__float_as_int(x), (4 << 10) | 0x1F));
}

__global__ __launch_bounds__(256, 1) void crf_forward(
    const float* __restrict__ emissions,   // [64, 512, 128]
    const float* __restrict__ transitions, // [128, 128]
    const float* __restrict__ start_t,     // [128]
    const float* __restrict__ end_t,       // [128]
    const int*   __restrict__ lengths,     // [64]
    float* __restrict__ out)               // [64]
{
    constexpr int N = 128;
    constexpr int L = 512;
    constexpr int PW = 20;   // 16 floats + 4 pad per chunk (80 B, 16B-aligned)
    const int b   = blockIdx.x;
    const int tid = threadIdx.x;
    const int g   = tid >> 3;            // j-group: j in [4g, 4g+4)
    const int k   = tid & 7;             // i-chunk: i in [16k, 16k+16)
    const int jw  = 4 * g + (k & 3);     // this lane's output tag (writer iff k<4)

    __shared__ alignas(16) float pbuf[2][8 * PW];
    __shared__ float wsum[2];

    // ---- one-time: E tile in registers as float2 column-pairs.
    f2 E01[16], E23[16];
    {
        const float* tb = transitions + (size_t)(16 * k) * N + 4 * g;
        #pragma unroll
        for (int ii = 0; ii < 16; ++ii) {
            float4 tv = *reinterpret_cast<const float4*>(tb + (size_t)ii * N);
            E01[ii].x = __builtin_amdgcn_exp2f(tv.x * LOG2E);
            E01[ii].y = __builtin_amdgcn_exp2f(tv.y * LOG2E);
            E23[ii].x = __builtin_amdgcn_exp2f(tv.z * LOG2E);
            E23[ii].y = __builtin_amdgcn_exp2f(tv.w * LOG2E);
        }
    }

    const int len = lengths[b];
    const float* eb = emissions + (size_t)b * L * N;

    // ---- init: q_j = exp2((start_j + e0_j)*log2e)
    if (tid < N) {
        float q = __builtin_amdgcn_exp2f((start_t[tid] + eb[tid]) * LOG2E);
        pbuf[0][(tid >> 4) * PW + (tid & 15)] = q;
    }
    int o = 0;
    int cur = 0;
    LDS_BARRIER();

    auto clampt = [&](int tt) { return tt < len ? tt : len - 1; };
    auto ldE = [&](int tt) { return eb[(size_t)tt * N + jw]; };

    auto STEP = [&](float e_cur) {
        // normalizer source + my 16-float chunk (4x b128, disjoint banks)
        float p0 = pbuf[cur][0];
        const float4* pv = reinterpret_cast<const float4*>(&pbuf[cur][k * PW]);
        float4 v0 = pv[0], v1 = pv[1], v2 = pv[2], v3 = pv[3];

        float expE = __builtin_amdgcn_exp2f(e_cur * LOG2E);
        int eS = (int)((__float_as_uint(p0) >> 23) & 0xFFu) - 127;
        o += eS;
        float scale = __uint_as_float((unsigned)(127 - eS) << 23);
        float es = expE * scale;   // computed during the dot, off the tail

        // two packed dot products over the 16i x 4j tile (v_pk_fma_f32)
        f2 d01 = {0.f, 0.f}, d23 = {0.f, 0.f};
        float4 vv[4] = {v0, v1, v2, v3};
        #pragma unroll
        for (int w = 0; w < 4; ++w) {
            #pragma unroll
            for (int e = 0; e < 4; ++e) {
                float pe = (&vv[w].x)[e];
                f2 pp = {pe, pe};
                const int ii = w * 4 + e;
                d01 = __builtin_elementwise_fma(pp, E01[ii], d01);
                d23 = __builtin_elementwise_fma(pp, E23[ii], d23);
            }
        }

        // quad butterfly (DPP), then select column, then single xor4 swizzle
        d01 += dpp_f2<0xB1>(d01); d23 += dpp_f2<0xB1>(d23);
        d01 += dpp_f2<0x4E>(d01); d23 += dpp_f2<0x4E>(d23);
        f2    dsel = (k & 2) ? d23 : d01;
        float dm   = (k & 1) ? dsel.y : dsel.x;
        dm += swz_xor4(dm);

        float pn = es * dm;
        cur ^= 1;
        if (k < 4) pbuf[cur][(jw >> 4) * PW + (jw & 15)] = pn;
        LDS_BARRIER();
    };

    // ---- main loop: distance-4 emission prefetch, manual 4-way unroll
    float ra = ldE(clampt(1));
    float rb = ldE(clampt(2));
    float rc = ldE(clampt(3));
    float rd = ldE(clampt(4));

    int t = 1;
    while (t < len) {
        STEP(ra); ra = ldE(clampt(t + 4)); ++t; if (t >= len) break;
        STEP(rb); rb = ldE(clampt(t + 4)); ++t; if (t >= len) break;
        STEP(rc); rc = ldE(clampt(t + 4)); ++t; if (t >= len) break;
        STEP(rd); rd = ldE(clampt(t + 4)); ++t;
    }

    // ---- finalize: out[b] = ln2 * (o + log2(sum_j q_j * exp2(end_j*log2e)))
    if (tid < N) {
        float q = pbuf[cur][(tid >> 4) * PW + (tid & 15)];
        float vend = q * __builtin_amdgcn_exp2f(end_t[tid] * LOG2E);
        #pragma unroll
        for (int m = 1; m < 64; m <<= 1) vend += __shfl_xor(vend, m);
        if ((tid & 63) == 0) wsum[tid >> 6] = vend;
    }
    LDS_BARRIER();
    if (tid == 0)
        out[b] = LN2 * ((float)o + __builtin_amdgcn_logf(wsum[0] + wsum[1]));
}

extern "C" void kernel_launch(void* const* d_in, const int* in_sizes, int n_in,
                              void* d_out, int out_size, void* d_ws, size_t ws_size,
                              hipStream_t stream) {
    const float* emissions   = (const float*)d_in[0];
    const float* transitions = (const float*)d_in[1];
    const float* start_t     = (const float*)d_in[2];
    const float* end_t       = (const float*)d_in[3];
    const int*   lengths     = (const int*)d_in[4];
    float* out = (float*)d_out;

    crf_forward<<<dim3(64), dim3(256), 0, stream>>>(
        emissions, transitions, start_t, end_t, lengths, out);
}